// Round 1
// baseline (536.084 us; speedup 1.0000x reference)
//
#include <hip/hip_runtime.h>
#include <math.h>

typedef unsigned short ushort;
typedef unsigned int uint;
typedef __attribute__((ext_vector_type(8))) short short8;
typedef __attribute__((ext_vector_type(4))) float f32x4;
typedef __attribute__((ext_vector_type(4))) ushort us4;

constexpr int BS = 2, C_IN = 8, CTX = 1024, TGT = 96;
constexpr int DM = 256, NH = 16, DFF = 1024, NL = 4;
constexpr int NF = 256, TOTAL = 320;
constexpr int NB = 16;
constexpr int DK = 16;
constexpr float EPS = 1e-5f;
constexpr float SCALE = 0.25f;
constexpr int KHEAD = DM * TOTAL;  // 81920
constexpr int M = NB * TOTAL;      // 5120

__device__ __forceinline__ ushort f2b(float x) {
    uint u = __float_as_uint(x);
    u += 0x7fff + ((u >> 16) & 1);
    return (ushort)(u >> 16);
}
__device__ __forceinline__ float bu2f(ushort x) { return __uint_as_float(((uint)x) << 16); }
__device__ __forceinline__ uint pack2(float a, float b) { return (uint)f2b(a) | ((uint)f2b(b) << 16); }

// async 16B global->LDS (DMA, no VGPR round-trip). LDS dest = wave-uniform base + lane*16.
typedef __attribute__((address_space(3))) uint lds_u32;
typedef const __attribute__((address_space(1))) uint glb_u32;
__device__ __forceinline__ void ldst16(const void* g, void* l) {
    __builtin_amdgcn_global_load_lds((glb_u32*)g, (lds_u32*)l, 16, 0, 0);
}

// ---------------- weight conversions + RevIN + patch-embed + out-init in ONE launch ----------------
__global__ void k_prep(const float* __restrict__ WQ, const float* __restrict__ WK,
                       const float* __restrict__ WV, const float* __restrict__ WO,
                       const float* __restrict__ F1, const float* __restrict__ F2,
                       const float* __restrict__ Wh,
                       ushort* __restrict__ Wtqkv, ushort* __restrict__ WtO,
                       ushort* __restrict__ Ft1, ushort* __restrict__ Ft2,
                       ushort* __restrict__ WhT2,
                       const float* __restrict__ z, const float* __restrict__ rw,
                       const float* __restrict__ rb,
                       const float* __restrict__ Wf, const float* __restrict__ bfv,
                       const float* __restrict__ Wc, const float* __restrict__ bcv,
                       const float* __restrict__ Wpos, ushort* __restrict__ u,
                       const float* __restrict__ bhv, float* __restrict__ outp,
                       float* __restrict__ scalef) {
    __shared__ ushort tile[32][33];
    __shared__ float rr1[16], rr2[16], bcast[2];
    __shared__ float szn[1024];
    int i = blockIdx.x;
    int tx = threadIdx.x, ty = threadIdx.y;
    if (i < 1024) {
        int zz = i >> 6, w = zz >> 2, l = zz & 3;
        const float* src = (w == 0 ? WQ : (w == 1 ? WK : (w == 2 ? WV : WO))) + l * 65536;
        ushort* dst = (w < 3) ? (Wtqkv + (size_t)l * 768 * 256 + w * 256 * 256)
                              : (WtO + (size_t)l * 65536);
        int c0 = (i & 7) * 32, r0 = ((i >> 3) & 7) * 32;
        tile[ty][tx] = f2b(src[(r0 + ty) * 256 + c0 + tx]);
        __syncthreads();
        dst[(c0 + ty) * 256 + r0 + tx] = tile[tx][ty];
    } else if (i < 2048) {
        int j = i - 1024, l = j >> 8;
        const float* src = F1 + (size_t)l * 262144;
        ushort* dst = Ft1 + (size_t)l * 262144;
        int c0 = (j & 31) * 32, r0 = ((j >> 5) & 7) * 32;
        tile[ty][tx] = f2b(src[(r0 + ty) * 1024 + c0 + tx]);
        __syncthreads();
        dst[(c0 + ty) * 256 + r0 + tx] = tile[tx][ty];
    } else if (i < 3072) {
        int j = i - 2048, l = j >> 8;
        const float* src = F2 + (size_t)l * 262144;
        ushort* dst = Ft2 + (size_t)l * 262144;
        int c0 = (j & 7) * 32, r0 = ((j >> 3) & 31) * 32;
        tile[ty][tx] = f2b(src[(r0 + ty) * 256 + c0 + tx]);
        __syncthreads();
        dst[(c0 + ty) * 1024 + r0 + tx] = tile[tx][ty];
    } else if (i < 10752) {
        int j = i - 3072;
        int t0 = (j % 3) * 32, rest = j / 3;
        int d0 = (rest & 7) * 32, pp = rest >> 3;
        tile[ty][tx] = f2b(Wh[((size_t)(d0 + ty) * 320 + pp) * 96 + t0 + tx]);
        __syncthreads();
        WhT2[(size_t)(t0 + ty) * KHEAD + pp * 256 + d0 + tx] = tile[tx][ty];
    } else {
        int bc = i - 10752;
        int tid = ty * 32 + tx;
        float x = z[bc * CTX + tid];
        float s1 = x, s2 = x * x;
#pragma unroll
        for (int off = 1; off < 64; off <<= 1) {
            s1 += __shfl_xor(s1, off);
            s2 += __shfl_xor(s2, off);
        }
        if ((tid & 63) == 0) { rr1[tid >> 6] = s1; rr2[tid >> 6] = s2; }
        __syncthreads();
        if (tid == 0) {
            float a1 = 0.f, a2 = 0.f;
            for (int k = 0; k < 16; k++) { a1 += rr1[k]; a2 += rr2[k]; }
            float m = a1 * (1.0f / CTX);
            float var = a2 * (1.0f / CTX) - m * m;
            float sd = sqrtf(var + EPS);
            bcast[0] = m; bcast[1] = sd;
        }
        __syncthreads();
        float m = bcast[0], sd = bcast[1];
        int c = bc & 7;
        float w = rw[c], bb = rb[c];
        szn[tid] = (x - m) / sd * w + bb;
        // head-output init: out = (bh - rb)/(rw+eps^2)*sd + m ; partial scale for k_head
        if (tid < TGT) outp[bc * TGT + tid] = (bhv[tid] - bb) / (w + EPS * EPS) * sd + m;
        if (tid == 0) scalef[bc] = sd / (w + EPS * EPS);
        __syncthreads();
        // dual-scale patch embed + positional, straight from LDS zn
        for (int o = tid; o < TOTAL * DM; o += 1024) {
            int p = o >> 8, d = o & 255;
            float acc2;
            if (p < NF) {
                acc2 = bfv[d];
                int base = p * 4;
#pragma unroll
                for (int q = 0; q < 8; q++)
                    acc2 += szn[min(base + q, CTX - 1)] * Wf[q * DM + d];
            } else {
                acc2 = bcv[d];
                int base = (p - NF) * 16;
#pragma unroll
                for (int q = 0; q < 32; q++)
                    acc2 += szn[min(base + q, CTX - 1)] * Wc[q * DM + d];
            }
            acc2 += Wpos[p * DM + d];
            u[((size_t)bc * TOTAL + p) * DM + d] = f2b(acc2);
        }
    }
}

// ---------------- bf16 MFMA GEMM, 64x64 tile, async LDS staging + XOR swizzle ----------------
// LDS slot (row, p) holds logical k-chunk p ^ ((row>>1)&3); frag read chunk = quad ^ ((l16>>1)&3).
template <int GELU, int QKV>
__global__ __launch_bounds__(256) void k_gemm_mfma(const ushort* __restrict__ A,
                                                   const ushort* __restrict__ Wt,
                                                   const float* __restrict__ b0,
                                                   const float* __restrict__ b1,
                                                   const float* __restrict__ b2,
                                                   ushort* __restrict__ C,
                                                   ushort* __restrict__ C2,
                                                   int Mm, int N, int K) {
    __shared__ ushort As[64][32];
    __shared__ ushort Bs[64][32];
    int tid = threadIdx.x;
    int wave = tid >> 6, lane = tid & 63;
    int quad = lane >> 4, l16 = lane & 15;
    int m0 = blockIdx.y * 64, n0 = blockIdx.x * 64;

    f32x4 acc[4];
#pragma unroll
    for (int nt = 0; nt < 4; nt++) acc[nt] = (f32x4){0.f, 0.f, 0.f, 0.f};

    int srow = wave * 16 + (lane >> 2);
    int sc = (lane & 3) ^ ((srow >> 1) & 3);
    ushort* AsW = &As[wave * 16][0];
    ushort* BsW = &Bs[wave * 16][0];
    const ushort* Ag = &A[(size_t)(m0 + srow) * K + sc * 8];
    const ushort* Bg = &Wt[(size_t)(n0 + srow) * K + sc * 8];
    int rchunk = (quad ^ ((l16 >> 1) & 3)) * 8;

    for (int k0 = 0; k0 < K; k0 += 32) {
        ldst16(Ag + k0, AsW);
        ldst16(Bg + k0, BsW);
        __syncthreads();
        short8 af = *(const short8*)&As[wave * 16 + l16][rchunk];
#pragma unroll
        for (int nt = 0; nt < 4; nt++) {
            short8 bf = *(const short8*)&Bs[nt * 16 + l16][rchunk];
            acc[nt] = __builtin_amdgcn_mfma_f32_16x16x32_bf16(af, bf, acc[nt], 0, 0, 0);
        }
        __syncthreads();
    }
#pragma unroll
    for (int nt = 0; nt < 4; nt++) {
        int col = n0 + nt * 16 + l16;
        float bi;
        if (QKV) {
            int bs = (n0 + nt * 16) >> 8;
            const float* bp = bs == 0 ? b0 : (bs == 1 ? b1 : b2);
            bi = bp[col & 255];
        } else {
            bi = b0[col];
        }
#pragma unroll
        for (int r = 0; r < 4; r++) {
            int rowm = m0 + wave * 16 + quad * 4 + r;
            float vv = acc[nt][r] + bi;
            if (GELU) vv = vv * 0.5f * (1.0f + erff(vv * 0.70710678118f));
            if (QKV) {
                int bs = col >> 8;
                ushort* dst = (bs == 2) ? (C2 + (size_t)rowm * DM)
                                        : (C + (size_t)bs * (M * DM) + (size_t)rowm * DM);
                dst[col & 255] = f2b(vv);
            } else {
                C[(size_t)rowm * N + col] = f2b(vv);
            }
        }
    }
}

// ---------------- GEMM(16x256) + bias + residual + LayerNorm, async staging ----------------
__global__ __launch_bounds__(256) void k_gemm_ln16(const ushort* __restrict__ A,
                                                   const ushort* __restrict__ Wt,
                                                   const float* __restrict__ bias,
                                                   const float* __restrict__ ls,
                                                   const float* __restrict__ lb,
                                                   ushort* __restrict__ u, int K) {
    __shared__ ushort As[16][32];
    __shared__ ushort Bs[256][32];
    __shared__ float ps1[16][4], ps2[16][4];
    int tid = threadIdx.x;
    int wave = tid >> 6, lane = tid & 63;
    int quad = lane >> 4, l16 = lane & 15;
    int m0 = blockIdx.x * 16;

    f32x4 acc[4];
#pragma unroll
    for (int nt = 0; nt < 4; nt++) acc[nt] = (f32x4){0.f, 0.f, 0.f, 0.f};

    int brow = wave * 16 + (lane >> 2);
    int bc_swz = (lane & 3) ^ ((brow >> 1) & 3);
    const ushort* Bg0 = &Wt[(size_t)brow * K + bc_swz * 8];
    ushort* BsW0 = &Bs[wave * 16][0];
    int ar = lane >> 2;
    int ac = (lane & 3) ^ ((ar >> 1) & 3);
    const ushort* Ag = &A[(size_t)(m0 + ar) * K + ac * 8];
    int rchunk = (quad ^ ((l16 >> 1) & 3)) * 8;

    for (int k0 = 0; k0 < K; k0 += 32) {
        if (tid < 64) ldst16(Ag + k0, &As[0][0]);
#pragma unroll
        for (int i = 0; i < 4; i++)
            ldst16(Bg0 + (size_t)i * 64 * K + k0, BsW0 + i * 64 * 32);
        __syncthreads();
        short8 af = *(const short8*)&As[l16][rchunk];
#pragma unroll
        for (int nt = 0; nt < 4; nt++) {
            short8 bf = *(const short8*)&Bs[wave * 64 + nt * 16 + l16][rchunk];
            acc[nt] = __builtin_amdgcn_mfma_f32_16x16x32_bf16(af, bf, acc[nt], 0, 0, 0);
        }
        __syncthreads();
    }
    float xv[4][4];
#pragma unroll
    for (int r = 0; r < 4; r++) {
        int rowg = m0 + quad * 4 + r;
        float s1 = 0.f, s2 = 0.f;
#pragma unroll
        for (int nt = 0; nt < 4; nt++) {
            int col = wave * 64 + nt * 16 + l16;
            float x = acc[nt][r] + bias[col] + bu2f(u[(size_t)rowg * DM + col]);
            xv[r][nt] = x; s1 += x; s2 += x * x;
        }
        s1 += __shfl_xor(s1, 1); s2 += __shfl_xor(s2, 1);
        s1 += __shfl_xor(s1, 2); s2 += __shfl_xor(s2, 2);
        s1 += __shfl_xor(s1, 4); s2 += __shfl_xor(s2, 4);
        s1 += __shfl_xor(s1, 8); s2 += __shfl_xor(s2, 8);
        if (l16 == 0) { ps1[quad * 4 + r][wave] = s1; ps2[quad * 4 + r][wave] = s2; }
    }
    __syncthreads();
#pragma unroll
    for (int r = 0; r < 4; r++) {
        int rowl = quad * 4 + r, rowg = m0 + rowl;
        float s1 = ps1[rowl][0] + ps1[rowl][1] + ps1[rowl][2] + ps1[rowl][3];
        float s2 = ps2[rowl][0] + ps2[rowl][1] + ps2[rowl][2] + ps2[rowl][3];
        float m = s1 * (1.0f / DM);
        float var = s2 * (1.0f / DM) - m * m;
        float rs = rsqrtf(var + EPS);
#pragma unroll
        for (int nt = 0; nt < 4; nt++) {
            int col = wave * 64 + nt * 16 + l16;
            u[(size_t)rowg * DM + col] = f2b((xv[r][nt] - m) * rs * ls[col] + lb[col]);
        }
    }
}

// ---------------- MFMA fused attention v6: residual scores RECOMPUTED (no sp round-trip) ----------------
// Layer l accumulates sum_{j<=l} Q_j K_j^T in f32 regs, looping over per-layer Q/K slots.
__global__ __launch_bounds__(256, 4) void k_attn(const ushort* __restrict__ qk, const ushort* __restrict__ vm,
                                                 ushort* __restrict__ ao, int nj) {
    __shared__ ushort sh[10240];
    uint* sh32 = (uint*)sh;
    int bh = blockIdx.x, b = bh >> 4, h = bh & 15;
    int i0 = blockIdx.y * 64;
    int t = threadIdx.x, wave = t >> 6, lane = t & 63, quad = lane >> 4, l16 = lane & 15;
    const short8 zero8 = (short8){0, 0, 0, 0, 0, 0, 0, 0};

    f32x4 acc[20];
#pragma unroll
    for (int nt = 0; nt < 20; nt++) acc[nt] = (f32x4){0.f, 0.f, 0.f, 0.f};

    // stage V once (region sh[5120..10240), disjoint from K region)
    for (int idx = t; idx < 320; idx += 256) {
        int jp = idx >> 1, dh = idx & 1;
        int j = jp * 2;
        uint4 a = *(const uint4*)&vm[((size_t)b * TOTAL + j) * DM + h * DK + dh * 8];
        uint4 bb = *(const uint4*)&vm[((size_t)b * TOTAL + j + 1) * DM + h * DK + dh * 8];
        const ushort* ap = (const ushort*)&a;
        const ushort* bp = (const ushort*)&bb;
        int jr = j & 31;
        int q = (jr & 15) >> 2, jj = ((jr >> 4) << 2) + (jr & 3);
        int base = 5120 + ((j >> 5) * 4 + q) * 128 + jj;
#pragma unroll
        for (int dd = 0; dd < 8; dd++) {
            int d = dh * 8 + dd;
            uint val = (uint)ap[dd] | ((uint)bp[dd] << 16);
            sh32[(base + d * 8) >> 1] = val;
        }
    }

    for (int jl = 0; jl < nj; jl++) {
        const ushort* qm = qk + (size_t)(2 * jl) * M * DM;
        const ushort* km = qm + (size_t)M * DM;
        for (int idx = t; idx < 640; idx += 256) {
            int j = idx >> 1, half = idx & 1;
            short8 kv = *(const short8*)&km[((size_t)b * TOTAL + j) * DM + h * DK + half * 8];
            int jt = j >> 4, jln = j & 15;
            *(short8*)&sh[((jt * 2 + half) * 16 + jln) * 8] = kv;
        }
        short8 qf = zero8;
        if (quad < 2) qf = *(const short8*)&qm[((size_t)b * TOTAL + i0 + wave * 16 + l16) * DM + h * DK + quad * 8];
        __syncthreads();
#pragma unroll
        for (int nt = 0; nt < 20; nt++) {
            short8 kf = *(const short8*)&sh[((nt * 2 + (quad & 1)) * 16 + l16) * 8];
            acc[nt] = __builtin_amdgcn_mfma_f32_16x16x32_bf16(kf, qf, acc[nt], 0, 0, 0);
        }
        __syncthreads();
    }

    float mx = -1e30f;
#pragma unroll
    for (int nt = 0; nt < 20; nt++)
#pragma unroll
        for (int r = 0; r < 4; r++) { acc[nt][r] *= SCALE; mx = fmaxf(mx, acc[nt][r]); }
    mx = fmaxf(mx, __shfl_xor(mx, 16));
    mx = fmaxf(mx, __shfl_xor(mx, 32));
    float sum = 0.f;
#pragma unroll
    for (int nt = 0; nt < 20; nt++)
#pragma unroll
        for (int r = 0; r < 4; r++) { acc[nt][r] = __expf(acc[nt][r] - mx); sum += acc[nt][r]; }
    sum += __shfl_xor(sum, 16);
    sum += __shfl_xor(sum, 32);
    float inv = 1.f / sum;
#pragma unroll
    for (int nt = 0; nt < 20; nt++)
#pragma unroll
        for (int r = 0; r < 4; r++) acc[nt][r] *= inv;

    f32x4 oacc = (f32x4){0.f, 0.f, 0.f, 0.f};
#pragma unroll
    for (int jt2 = 0; jt2 < 10; jt2++) {
        short8 vt = *(const short8*)&sh[5120 + ((jt2 * 4 + quad) * 16 + l16) * 8];
        union { short8 v; uint u[4]; } pf;
        pf.u[0] = pack2(acc[2 * jt2][0], acc[2 * jt2][1]);
        pf.u[1] = pack2(acc[2 * jt2][2], acc[2 * jt2][3]);
        pf.u[2] = pack2(acc[2 * jt2 + 1][0], acc[2 * jt2 + 1][1]);
        pf.u[3] = pack2(acc[2 * jt2 + 1][2], acc[2 * jt2 + 1][3]);
        oacc = __builtin_amdgcn_mfma_f32_16x16x32_bf16(vt, pf.v, oacc, 0, 0, 0);
    }
    us4 ov4 = (us4){f2b(oacc[0]), f2b(oacc[1]), f2b(oacc[2]), f2b(oacc[3])};
    *(us4*)&ao[((size_t)b * TOTAL + i0 + wave * 16 + l16) * DM + h * DK + quad * 4] = ov4;
}

// ---------------- head GEMM: MFMA split-K, atomic accumulate into pre-initialized out ----------------
__global__ __launch_bounds__(256) void k_head(const ushort* __restrict__ u, const ushort* __restrict__ WhT2,
                                              const float* __restrict__ scalef, float* __restrict__ out) {
    int t0 = blockIdx.x * 16;
    int wave = threadIdx.x >> 6, lane = threadIdx.x & 63;
    int quad = lane >> 4, l16 = lane & 15;
    int chunk = blockIdx.y * 4 + wave;
    int kbeg = chunk * 1024;
    f32x4 acc = (f32x4){0.f, 0.f, 0.f, 0.f};
    const ushort* za = &u[(size_t)l16 * KHEAD + quad * 8];
    const ushort* wb = &WhT2[(size_t)(t0 + l16) * KHEAD + quad * 8];
#pragma unroll 4
    for (int k = kbeg; k < kbeg + 1024; k += 32) {
        short8 af = *(const short8*)&za[k];
        short8 bf = *(const short8*)&wb[k];
        acc = __builtin_amdgcn_mfma_f32_16x16x32_bf16(af, bf, acc, 0, 0, 0);
    }
#pragma unroll
    for (int r = 0; r < 4; r++) {
        int bcr = quad * 4 + r;
        atomicAdd(&out[bcr * TGT + t0 + l16], acc[r] * scalef[bcr]);
    }
}

extern "C" void kernel_launch(void* const* d_in, const int* in_sizes, int n_in,
                              void* d_out, int out_size, void* d_ws, size_t ws_size,
                              hipStream_t stream) {
    const float* z       = (const float*)d_in[0];
    const float* revin_w = (const float*)d_in[1];
    const float* revin_b = (const float*)d_in[2];
    const float* Wf      = (const float*)d_in[3];
    const float* bfv     = (const float*)d_in[4];
    const float* Wc      = (const float*)d_in[5];
    const float* bcv     = (const float*)d_in[6];
    const float* Wpos    = (const float*)d_in[7];
    const float* WQ      = (const float*)d_in[8];
    const float* bQ      = (const float*)d_in[9];
    const float* WK      = (const float*)d_in[10];
    const float* bK      = (const float*)d_in[11];
    const float* WV      = (const float*)d_in[12];
    const float* bV      = (const float*)d_in[13];
    const float* WO      = (const float*)d_in[14];
    const float* bO      = (const float*)d_in[15];
    const float* ln1s    = (const float*)d_in[16];
    const float* ln1b    = (const float*)d_in[17];
    const float* ln2s    = (const float*)d_in[18];
    const float* ln2b    = (const float*)d_in[19];
    const float* F1      = (const float*)d_in[20];
    const float* c1      = (const float*)d_in[21];
    const float* F2      = (const float*)d_in[22];
    const float* c2      = (const float*)d_in[23];
    const float* Wh      = (const float*)d_in[24];
    const float* bh      = (const float*)d_in[25];
    float* out = (float*)d_out;

    char* p = (char*)d_ws;
    float* scalef = (float*)p;   p += 16 * 4;
    p = (char*)(((size_t)p + 255) & ~255ull);
    ushort* u     = (ushort*)p;  p += (size_t)M * DM * 2;
    ushort* qkbuf = (ushort*)p;  p += (size_t)NL * 2 * M * DM * 2;   // per-layer [Q_l, K_l]
    ushort* vbuf  = (ushort*)p;  p += (size_t)M * DM * 2;
    ushort* ax    = (ushort*)p;  p += (size_t)M * DM * 2;
    ushort* hbuf  = (ushort*)p;  p += (size_t)M * DFF * 2;
    ushort* Wtqkv = (ushort*)p;  p += (size_t)NL * 768 * 256 * 2;
    ushort* WtO   = (ushort*)p;  p += (size_t)NL * 256 * 256 * 2;
    ushort* Ft1   = (ushort*)p;  p += (size_t)NL * 1024 * 256 * 2;
    ushort* Ft2   = (ushort*)p;  p += (size_t)NL * 256 * 1024 * 2;
    ushort* WhT2  = (ushort*)p;  p += (size_t)TGT * KHEAD * 2;

    k_prep<<<10768, dim3(32, 32), 0, stream>>>(WQ, WK, WV, WO, F1, F2, Wh,
                                               Wtqkv, WtO, Ft1, Ft2, WhT2,
                                               z, revin_w, revin_b,
                                               Wf, bfv, Wc, bcv, Wpos, u,
                                               bh, out, scalef);

    for (int l = 0; l < NL; l++) {
        k_gemm_mfma<0, 1><<<dim3(12, 80), 256, 0, stream>>>(
            u, Wtqkv + (size_t)l * 768 * 256, bQ + l * DM, bK + l * DM, bV + l * DM,
            qkbuf + (size_t)l * 2 * M * DM, vbuf, M, 768, 256);
        k_attn<<<dim3(NB * NH, 5), 256, 0, stream>>>(qkbuf, vbuf, ax, l + 1);
        k_gemm_ln16<<<M / 16, 256, 0, stream>>>(
            ax, WtO + (size_t)l * 65536, bO + l * DM, ln1s + l * DM, ln1b + l * DM, u, 256);
        k_gemm_mfma<1, 0><<<dim3(16, 80), 256, 0, stream>>>(
            u, Ft1 + (size_t)l * 262144, c1 + l * DFF, c1, c1, hbuf, hbuf, M, 1024, 256);
        k_gemm_ln16<<<M / 16, 256, 0, stream>>>(
            hbuf, Ft2 + (size_t)l * 262144, c2 + l * DM, ln2s + l * DM, ln2b + l * DM, u, 1024);
    }

    k_head<<<dim3(TGT / 16, 20), 256, 0, stream>>>(u, WhT2, scalef, out);
}

// Round 2
// 459.419 us; speedup vs baseline: 1.1669x; 1.1669x over previous
//
#include <hip/hip_runtime.h>
#include <math.h>

typedef unsigned short ushort;
typedef unsigned int uint;
typedef __attribute__((ext_vector_type(8))) short short8;
typedef __attribute__((ext_vector_type(4))) float f32x4;
typedef __attribute__((ext_vector_type(4))) ushort us4;

constexpr int BS = 2, C_IN = 8, CTX = 1024, TGT = 96;
constexpr int DM = 256, NH = 16, DFF = 1024, NL = 4;
constexpr int NF = 256, TOTAL = 320;
constexpr int NB = 16;
constexpr int DK = 16;
constexpr float EPS = 1e-5f;
constexpr float SCALE = 0.25f;
constexpr int KHEAD = DM * TOTAL;  // 81920
constexpr int M = NB * TOTAL;      // 5120

__device__ __forceinline__ ushort f2b(float x) {
    uint u = __float_as_uint(x);
    u += 0x7fff + ((u >> 16) & 1);
    return (ushort)(u >> 16);
}
__device__ __forceinline__ float bu2f(ushort x) { return __uint_as_float(((uint)x) << 16); }
__device__ __forceinline__ uint pack2(float a, float b) { return (uint)f2b(a) | ((uint)f2b(b) << 16); }

// async 16B global->LDS (DMA, no VGPR round-trip). LDS dest = wave-uniform base + lane*16.
typedef __attribute__((address_space(3))) uint lds_u32;
typedef const __attribute__((address_space(1))) uint glb_u32;
__device__ __forceinline__ void ldst16(const void* g, void* l) {
    __builtin_amdgcn_global_load_lds((glb_u32*)g, (lds_u32*)l, 16, 0, 0);
}

// ---------------- weight conversions + RevIN + out-init in ONE launch ----------------
__global__ void k_prep(const float* __restrict__ WQ, const float* __restrict__ WK,
                       const float* __restrict__ WV, const float* __restrict__ WO,
                       const float* __restrict__ F1, const float* __restrict__ F2,
                       const float* __restrict__ Wh,
                       ushort* __restrict__ Wtqkv, ushort* __restrict__ WtO,
                       ushort* __restrict__ Ft1, ushort* __restrict__ Ft2,
                       ushort* __restrict__ WhT2,
                       const float* __restrict__ z, const float* __restrict__ rw,
                       const float* __restrict__ rb, float* __restrict__ zn,
                       const float* __restrict__ bhv, float* __restrict__ outp,
                       float* __restrict__ scalef) {
    __shared__ ushort tile[32][33];
    __shared__ float rr1[16], rr2[16], bcast[2];
    int i = blockIdx.x;
    int tx = threadIdx.x, ty = threadIdx.y;
    if (i < 1024) {
        int zz = i >> 6, w = zz >> 2, l = zz & 3;
        const float* src = (w == 0 ? WQ : (w == 1 ? WK : (w == 2 ? WV : WO))) + l * 65536;
        ushort* dst = (w < 3) ? (Wtqkv + (size_t)l * 768 * 256 + w * 256 * 256)
                              : (WtO + (size_t)l * 65536);
        int c0 = (i & 7) * 32, r0 = ((i >> 3) & 7) * 32;
        tile[ty][tx] = f2b(src[(r0 + ty) * 256 + c0 + tx]);
        __syncthreads();
        dst[(c0 + ty) * 256 + r0 + tx] = tile[tx][ty];
    } else if (i < 2048) {
        int j = i - 1024, l = j >> 8;
        const float* src = F1 + (size_t)l * 262144;
        ushort* dst = Ft1 + (size_t)l * 262144;
        int c0 = (j & 31) * 32, r0 = ((j >> 5) & 7) * 32;
        tile[ty][tx] = f2b(src[(r0 + ty) * 1024 + c0 + tx]);
        __syncthreads();
        dst[(c0 + ty) * 256 + r0 + tx] = tile[tx][ty];
    } else if (i < 3072) {
        int j = i - 2048, l = j >> 8;
        const float* src = F2 + (size_t)l * 262144;
        ushort* dst = Ft2 + (size_t)l * 262144;
        int c0 = (j & 7) * 32, r0 = ((j >> 3) & 31) * 32;
        tile[ty][tx] = f2b(src[(r0 + ty) * 256 + c0 + tx]);
        __syncthreads();
        dst[(c0 + ty) * 1024 + r0 + tx] = tile[tx][ty];
    } else if (i < 10752) {
        int j = i - 3072;
        int t0 = (j % 3) * 32, rest = j / 3;
        int d0 = (rest & 7) * 32, pp = rest >> 3;
        tile[ty][tx] = f2b(Wh[((size_t)(d0 + ty) * 320 + pp) * 96 + t0 + tx]);
        __syncthreads();
        WhT2[(size_t)(t0 + ty) * KHEAD + pp * 256 + d0 + tx] = tile[tx][ty];
    } else {
        int bc = i - 10752;
        int tid = ty * 32 + tx;
        float x = z[bc * CTX + tid];
        float s1 = x, s2 = x * x;
#pragma unroll
        for (int off = 1; off < 64; off <<= 1) {
            s1 += __shfl_xor(s1, off);
            s2 += __shfl_xor(s2, off);
        }
        if ((tid & 63) == 0) { rr1[tid >> 6] = s1; rr2[tid >> 6] = s2; }
        __syncthreads();
        if (tid == 0) {
            float a1 = 0.f, a2 = 0.f;
            for (int k = 0; k < 16; k++) { a1 += rr1[k]; a2 += rr2[k]; }
            float m = a1 * (1.0f / CTX);
            float var = a2 * (1.0f / CTX) - m * m;
            float sd = sqrtf(var + EPS);
            bcast[0] = m; bcast[1] = sd;
        }
        __syncthreads();
        float m = bcast[0], sd = bcast[1];
        int c = bc & 7;
        float w = rw[c], bb = rb[c];
        zn[bc * CTX + tid] = (x - m) / sd * w + bb;
        // head-output init: out = (bh - rb)/(rw+eps^2)*sd + m ; scale factor for k_head
        if (tid < TGT) outp[bc * TGT + tid] = (bhv[tid] - bb) / (w + EPS * EPS) * sd + m;
        if (tid == 0) scalef[bc] = sd / (w + EPS * EPS);
    }
}

// ---------------- dual-scale patch embed + positional -> bf16 u ----------------
__global__ void k_embed(const float* __restrict__ zn, const float* __restrict__ Wf,
                        const float* __restrict__ bfv, const float* __restrict__ Wc,
                        const float* __restrict__ bcv, const float* __restrict__ Wpos,
                        ushort* __restrict__ u) {
    int bc = blockIdx.x / TOTAL, p = blockIdx.x % TOTAL, d = threadIdx.x;
    float acc;
    if (p < NF) {
        acc = bfv[d];
        int base = p * 4;
        for (int i = 0; i < 8; i++) {
            int idx = min(base + i, CTX - 1);
            acc += zn[bc * CTX + idx] * Wf[i * DM + d];
        }
    } else {
        int pc = p - NF;
        acc = bcv[d];
        int base = pc * 16;
        for (int i = 0; i < 32; i++) {
            int idx = min(base + i, CTX - 1);
            acc += zn[bc * CTX + idx] * Wc[i * DM + d];
        }
    }
    acc += Wpos[p * DM + d];
    u[(bc * TOTAL + p) * DM + d] = f2b(acc);
}

// ---------------- bf16 MFMA GEMM, 64x64 tile, async LDS staging + XOR swizzle ----------------
template <int GELU, int QKV>
__global__ __launch_bounds__(256) void k_gemm_mfma(const ushort* __restrict__ A,
                                                   const ushort* __restrict__ Wt,
                                                   const float* __restrict__ b0,
                                                   const float* __restrict__ b1,
                                                   const float* __restrict__ b2,
                                                   ushort* __restrict__ C,
                                                   ushort* __restrict__ C2,
                                                   int Mm, int N, int K) {
    __shared__ ushort As[64][32];
    __shared__ ushort Bs[64][32];
    int tid = threadIdx.x;
    int wave = tid >> 6, lane = tid & 63;
    int quad = lane >> 4, l16 = lane & 15;
    int m0 = blockIdx.y * 64, n0 = blockIdx.x * 64;

    f32x4 acc[4];
#pragma unroll
    for (int nt = 0; nt < 4; nt++) acc[nt] = (f32x4){0.f, 0.f, 0.f, 0.f};

    int srow = wave * 16 + (lane >> 2);
    int sc = (lane & 3) ^ ((srow >> 1) & 3);
    ushort* AsW = &As[wave * 16][0];
    ushort* BsW = &Bs[wave * 16][0];
    const ushort* Ag = &A[(size_t)(m0 + srow) * K + sc * 8];
    const ushort* Bg = &Wt[(size_t)(n0 + srow) * K + sc * 8];
    int rchunk = (quad ^ ((l16 >> 1) & 3)) * 8;

    for (int k0 = 0; k0 < K; k0 += 32) {
        ldst16(Ag + k0, AsW);
        ldst16(Bg + k0, BsW);
        __syncthreads();
        short8 af = *(const short8*)&As[wave * 16 + l16][rchunk];
#pragma unroll
        for (int nt = 0; nt < 4; nt++) {
            short8 bf = *(const short8*)&Bs[nt * 16 + l16][rchunk];
            acc[nt] = __builtin_amdgcn_mfma_f32_16x16x32_bf16(af, bf, acc[nt], 0, 0, 0);
        }
        __syncthreads();
    }
#pragma unroll
    for (int nt = 0; nt < 4; nt++) {
        int col = n0 + nt * 16 + l16;
        float bi;
        if (QKV) {
            int bs = (n0 + nt * 16) >> 8;
            const float* bp = bs == 0 ? b0 : (bs == 1 ? b1 : b2);
            bi = bp[col & 255];
        } else {
            bi = b0[col];
        }
#pragma unroll
        for (int r = 0; r < 4; r++) {
            int rowm = m0 + wave * 16 + quad * 4 + r;
            float vv = acc[nt][r] + bi;
            if (GELU) vv = vv * 0.5f * (1.0f + erff(vv * 0.70710678118f));
            if (QKV) {
                int bs = col >> 8;
                ushort* dst = (bs == 2) ? (C2 + (size_t)rowm * DM)
                                        : (C + (size_t)bs * (M * DM) + (size_t)rowm * DM);
                dst[col & 255] = f2b(vv);
            } else {
                C[(size_t)rowm * N + col] = f2b(vv);
            }
        }
    }
}

// ---------------- GEMM(16x256) + bias + residual + LayerNorm, async staging ----------------
__global__ __launch_bounds__(256) void k_gemm_ln16(const ushort* __restrict__ A,
                                                   const ushort* __restrict__ Wt,
                                                   const float* __restrict__ bias,
                                                   const float* __restrict__ ls,
                                                   const float* __restrict__ lb,
                                                   ushort* __restrict__ u, int K) {
    __shared__ ushort As[16][32];
    __shared__ ushort Bs[256][32];
    __shared__ float ps1[16][4], ps2[16][4];
    int tid = threadIdx.x;
    int wave = tid >> 6, lane = tid & 63;
    int quad = lane >> 4, l16 = lane & 15;
    int m0 = blockIdx.x * 16;

    f32x4 acc[4];
#pragma unroll
    for (int nt = 0; nt < 4; nt++) acc[nt] = (f32x4){0.f, 0.f, 0.f, 0.f};

    int brow = wave * 16 + (lane >> 2);
    int bc_swz = (lane & 3) ^ ((brow >> 1) & 3);
    const ushort* Bg0 = &Wt[(size_t)brow * K + bc_swz * 8];
    ushort* BsW0 = &Bs[wave * 16][0];
    int ar = lane >> 2;
    int ac = (lane & 3) ^ ((ar >> 1) & 3);
    const ushort* Ag = &A[(size_t)(m0 + ar) * K + ac * 8];
    int rchunk = (quad ^ ((l16 >> 1) & 3)) * 8;

    for (int k0 = 0; k0 < K; k0 += 32) {
        if (tid < 64) ldst16(Ag + k0, &As[0][0]);
#pragma unroll
        for (int i = 0; i < 4; i++)
            ldst16(Bg0 + (size_t)i * 64 * K + k0, BsW0 + i * 64 * 32);
        __syncthreads();
        short8 af = *(const short8*)&As[l16][rchunk];
#pragma unroll
        for (int nt = 0; nt < 4; nt++) {
            short8 bf = *(const short8*)&Bs[wave * 64 + nt * 16 + l16][rchunk];
            acc[nt] = __builtin_amdgcn_mfma_f32_16x16x32_bf16(af, bf, acc[nt], 0, 0, 0);
        }
        __syncthreads();
    }
    float xv[4][4];
#pragma unroll
    for (int r = 0; r < 4; r++) {
        int rowg = m0 + quad * 4 + r;
        float s1 = 0.f, s2 = 0.f;
#pragma unroll
        for (int nt = 0; nt < 4; nt++) {
            int col = wave * 64 + nt * 16 + l16;
            float x = acc[nt][r] + bias[col] + bu2f(u[(size_t)rowg * DM + col]);
            xv[r][nt] = x; s1 += x; s2 += x * x;
        }
        s1 += __shfl_xor(s1, 1); s2 += __shfl_xor(s2, 1);
        s1 += __shfl_xor(s1, 2); s2 += __shfl_xor(s2, 2);
        s1 += __shfl_xor(s1, 4); s2 += __shfl_xor(s2, 4);
        s1 += __shfl_xor(s1, 8); s2 += __shfl_xor(s2, 8);
        if (l16 == 0) { ps1[quad * 4 + r][wave] = s1; ps2[quad * 4 + r][wave] = s2; }
    }
    __syncthreads();
#pragma unroll
    for (int r = 0; r < 4; r++) {
        int rowl = quad * 4 + r, rowg = m0 + rowl;
        float s1 = ps1[rowl][0] + ps1[rowl][1] + ps1[rowl][2] + ps1[rowl][3];
        float s2 = ps2[rowl][0] + ps2[rowl][1] + ps2[rowl][2] + ps2[rowl][3];
        float m = s1 * (1.0f / DM);
        float var = s2 * (1.0f / DM) - m * m;
        float rs = rsqrtf(var + EPS);
#pragma unroll
        for (int nt = 0; nt < 4; nt++) {
            int col = wave * 64 + nt * 16 + l16;
            u[(size_t)rowg * DM + col] = f2b((xv[r][nt] - m) * rs * ls[col] + lb[col]);
        }
    }
}

// ---------------- MFMA fused attention: residual scores RECOMPUTED (no sp round-trip) ----------------
// Layer l accumulates sum_{j<=l} Q_j K_j^T in f32 regs, looping over per-layer Q/K slots.
__global__ __launch_bounds__(256, 4) void k_attn(const ushort* __restrict__ qk, const ushort* __restrict__ vm,
                                                 ushort* __restrict__ ao, int nj) {
    __shared__ ushort sh[10240];
    uint* sh32 = (uint*)sh;
    int bh = blockIdx.x, b = bh >> 4, h = bh & 15;
    int i0 = blockIdx.y * 64;
    int t = threadIdx.x, wave = t >> 6, lane = t & 63, quad = lane >> 4, l16 = lane & 15;
    const short8 zero8 = (short8){0, 0, 0, 0, 0, 0, 0, 0};

    f32x4 acc[20];
#pragma unroll
    for (int nt = 0; nt < 20; nt++) acc[nt] = (f32x4){0.f, 0.f, 0.f, 0.f};

    // stage V once (region sh[5120..10240), disjoint from K region)
    for (int idx = t; idx < 320; idx += 256) {
        int jp = idx >> 1, dh = idx & 1;
        int j = jp * 2;
        uint4 a = *(const uint4*)&vm[((size_t)b * TOTAL + j) * DM + h * DK + dh * 8];
        uint4 bb = *(const uint4*)&vm[((size_t)b * TOTAL + j + 1) * DM + h * DK + dh * 8];
        const ushort* ap = (const ushort*)&a;
        const ushort* bp = (const ushort*)&bb;
        int jr = j & 31;
        int q = (jr & 15) >> 2, jj = ((jr >> 4) << 2) + (jr & 3);
        int base = 5120 + ((j >> 5) * 4 + q) * 128 + jj;
#pragma unroll
        for (int dd = 0; dd < 8; dd++) {
            int d = dh * 8 + dd;
            uint val = (uint)ap[dd] | ((uint)bp[dd] << 16);
            sh32[(base + d * 8) >> 1] = val;
        }
    }

    for (int jl = 0; jl < nj; jl++) {
        const ushort* qm = qk + (size_t)(2 * jl) * M * DM;
        const ushort* km = qm + (size_t)M * DM;
        for (int idx = t; idx < 640; idx += 256) {
            int j = idx >> 1, half = idx & 1;
            short8 kv = *(const short8*)&km[((size_t)b * TOTAL + j) * DM + h * DK + half * 8];
            int jt = j >> 4, jln = j & 15;
            *(short8*)&sh[((jt * 2 + half) * 16 + jln) * 8] = kv;
        }
        short8 qf = zero8;
        if (quad < 2) qf = *(const short8*)&qm[((size_t)b * TOTAL + i0 + wave * 16 + l16) * DM + h * DK + quad * 8];
        __syncthreads();
#pragma unroll
        for (int nt = 0; nt < 20; nt++) {
            short8 kf = *(const short8*)&sh[((nt * 2 + (quad & 1)) * 16 + l16) * 8];
            acc[nt] = __builtin_amdgcn_mfma_f32_16x16x32_bf16(kf, qf, acc[nt], 0, 0, 0);
        }
        __syncthreads();
    }

    float mx = -1e30f;
#pragma unroll
    for (int nt = 0; nt < 20; nt++)
#pragma unroll
        for (int r = 0; r < 4; r++) { acc[nt][r] *= SCALE; mx = fmaxf(mx, acc[nt][r]); }
    mx = fmaxf(mx, __shfl_xor(mx, 16));
    mx = fmaxf(mx, __shfl_xor(mx, 32));
    float sum = 0.f;
#pragma unroll
    for (int nt = 0; nt < 20; nt++)
#pragma unroll
        for (int r = 0; r < 4; r++) { acc[nt][r] = __expf(acc[nt][r] - mx); sum += acc[nt][r]; }
    sum += __shfl_xor(sum, 16);
    sum += __shfl_xor(sum, 32);
    float inv = 1.f / sum;
#pragma unroll
    for (int nt = 0; nt < 20; nt++)
#pragma unroll
        for (int r = 0; r < 4; r++) acc[nt][r] *= inv;

    f32x4 oacc = (f32x4){0.f, 0.f, 0.f, 0.f};
#pragma unroll
    for (int jt2 = 0; jt2 < 10; jt2++) {
        short8 vt = *(const short8*)&sh[5120 + ((jt2 * 4 + quad) * 16 + l16) * 8];
        union { short8 v; uint u[4]; } pf;
        pf.u[0] = pack2(acc[2 * jt2][0], acc[2 * jt2][1]);
        pf.u[1] = pack2(acc[2 * jt2][2], acc[2 * jt2][3]);
        pf.u[2] = pack2(acc[2 * jt2 + 1][0], acc[2 * jt2 + 1][1]);
        pf.u[3] = pack2(acc[2 * jt2 + 1][2], acc[2 * jt2 + 1][3]);
        oacc = __builtin_amdgcn_mfma_f32_16x16x32_bf16(vt, pf.v, oacc, 0, 0, 0);
    }
    us4 ov4 = (us4){f2b(oacc[0]), f2b(oacc[1]), f2b(oacc[2]), f2b(oacc[3])};
    *(us4*)&ao[((size_t)b * TOTAL + i0 + wave * 16 + l16) * DM + h * DK + quad * 4] = ov4;
}

// ---------------- head GEMM: MFMA split-K, atomic accumulate into pre-initialized out ----------------
__global__ __launch_bounds__(256) void k_head(const ushort* __restrict__ u, const ushort* __restrict__ WhT2,
                                              const float* __restrict__ scalef, float* __restrict__ out) {
    int t0 = blockIdx.x * 16;
    int wave = threadIdx.x >> 6, lane = threadIdx.x & 63;
    int quad = lane >> 4, l16 = lane & 15;
    int chunk = blockIdx.y * 4 + wave;
    int kbeg = chunk * 1024;
    f32x4 acc = (f32x4){0.f, 0.f, 0.f, 0.f};
    const ushort* za = &u[(size_t)l16 * KHEAD + quad * 8];
    const ushort* wb = &WhT2[(size_t)(t0 + l16) * KHEAD + quad * 8];
#pragma unroll 4
    for (int k = kbeg; k < kbeg + 1024; k += 32) {
        short8 af = *(const short8*)&za[k];
        short8 bf = *(const short8*)&wb[k];
        acc = __builtin_amdgcn_mfma_f32_16x16x32_bf16(af, bf, acc, 0, 0, 0);
    }
#pragma unroll
    for (int r = 0; r < 4; r++) {
        int bcr = quad * 4 + r;
        atomicAdd(&out[bcr * TGT + t0 + l16], acc[r] * scalef[bcr]);
    }
}

extern "C" void kernel_launch(void* const* d_in, const int* in_sizes, int n_in,
                              void* d_out, int out_size, void* d_ws, size_t ws_size,
                              hipStream_t stream) {
    const float* z       = (const float*)d_in[0];
    const float* revin_w = (const float*)d_in[1];
    const float* revin_b = (const float*)d_in[2];
    const float* Wf      = (const float*)d_in[3];
    const float* bfv     = (const float*)d_in[4];
    const float* Wc      = (const float*)d_in[5];
    const float* bcv     = (const float*)d_in[6];
    const float* Wpos    = (const float*)d_in[7];
    const float* WQ      = (const float*)d_in[8];
    const float* bQ      = (const float*)d_in[9];
    const float* WK      = (const float*)d_in[10];
    const float* bK      = (const float*)d_in[11];
    const float* WV      = (const float*)d_in[12];
    const float* bV      = (const float*)d_in[13];
    const float* WO      = (const float*)d_in[14];
    const float* bO      = (const float*)d_in[15];
    const float* ln1s    = (const float*)d_in[16];
    const float* ln1b    = (const float*)d_in[17];
    const float* ln2s    = (const float*)d_in[18];
    const float* ln2b    = (const float*)d_in[19];
    const float* F1      = (const float*)d_in[20];
    const float* c1      = (const float*)d_in[21];
    const float* F2      = (const float*)d_in[22];
    const float* c2      = (const float*)d_in[23];
    const float* Wh      = (const float*)d_in[24];
    const float* bh      = (const float*)d_in[25];
    float* out = (float*)d_out;

    char* p = (char*)d_ws;
    float* scalef = (float*)p;   p += 16 * 4;
    p = (char*)(((size_t)p + 255) & ~255ull);
    float* zn = (float*)p;       p += NB * CTX * 4;
    ushort* u     = (ushort*)p;  p += (size_t)M * DM * 2;
    ushort* qkbuf = (ushort*)p;  p += (size_t)NL * 2 * M * DM * 2;   // per-layer [Q_l, K_l]
    ushort* vbuf  = (ushort*)p;  p += (size_t)M * DM * 2;
    ushort* ax    = (ushort*)p;  p += (size_t)M * DM * 2;
    ushort* hbuf  = (ushort*)p;  p += (size_t)M * DFF * 2;
    ushort* Wtqkv = (ushort*)p;  p += (size_t)NL * 768 * 256 * 2;
    ushort* WtO   = (ushort*)p;  p += (size_t)NL * 256 * 256 * 2;
    ushort* Ft1   = (ushort*)p;  p += (size_t)NL * 1024 * 256 * 2;
    ushort* Ft2   = (ushort*)p;  p += (size_t)NL * 256 * 1024 * 2;
    ushort* WhT2  = (ushort*)p;  p += (size_t)TGT * KHEAD * 2;

    k_prep<<<10768, dim3(32, 32), 0, stream>>>(WQ, WK, WV, WO, F1, F2, Wh,
                                               Wtqkv, WtO, Ft1, Ft2, WhT2,
                                               z, revin_w, revin_b, zn,
                                               bh, out, scalef);
    k_embed<<<NB * TOTAL, 256, 0, stream>>>(zn, Wf, bfv, Wc, bcv, Wpos, u);

    for (int l = 0; l < NL; l++) {
        k_gemm_mfma<0, 1><<<dim3(12, 80), 256, 0, stream>>>(
            u, Wtqkv + (size_t)l * 768 * 256, bQ + l * DM, bK + l * DM, bV + l * DM,
            qkbuf + (size_t)l * 2 * M * DM, vbuf, M, 768, 256);
        k_attn<<<dim3(NB * NH, 5), 256, 0, stream>>>(qkbuf, vbuf, ax, l + 1);
        k_gemm_ln16<<<M / 16, 256, 0, stream>>>(
            ax, WtO + (size_t)l * 65536, bO + l * DM, ln1s + l * DM, ln1b + l * DM, u, 256);
        k_gemm_mfma<1, 0><<<dim3(16, 80), 256, 0, stream>>>(
            u, Ft1 + (size_t)l * 262144, c1 + l * DFF, c1, c1, hbuf, hbuf, M, 1024, 256);
        k_gemm_ln16<<<M / 16, 256, 0, stream>>>(
            hbuf, Ft2 + (size_t)l * 262144, c2 + l * DM, ln2s + l * DM, ln2b + l * DM, u, 1024);
    }

    k_head<<<dim3(TGT / 16, 20), 256, 0, stream>>>(u, WhT2, scalef, out);
}